// Round 14
// baseline (42.932 us; speedup 1.0000x reference)
//
#include <hip/hip_runtime.h>

// ClusteringLayer: q[n,k] = normalize_k( 1 / (1 + ||x_n - c_k||^2) )
// x: [65536,256] fp32, clusters: [256,256] fp32, out: [65536,256] fp32.
// R13: B-tax halved via 32x32x16 MFMA (1 KB B-frag feeds 32 rows, not 16).
// 2048 blocks x 64 thr (1 wave). Wave = 32 rows x 256 cols; zero barriers;
// A staged via wave-private 16 KB swizzled LDS (same-wave lgkm ordering);
// x2 accumulated from f16 A-frags inside the MFMA loop; B' = -2*clusters
// f16 fragments streamed from L2 (1 MB/CU total). launch_bounds(64,1)
// for the 512-reg budget tier (acc[8] f32x16 = 128 VGPRs).

typedef _Float16 f16x8 __attribute__((ext_vector_type(8)));
typedef _Float16 f16x4 __attribute__((ext_vector_type(4)));
typedef float    f32x4 __attribute__((ext_vector_type(4)));
typedef float    f32x16 __attribute__((ext_vector_type(16)));

#define DIM    256
#define NCLUST 256

// ---------------------------------------------------------------------------
// Pre-kernel: blocks 0..127 -> B' = (-2*clusters) as f16 32x32x16 fragments
//             blocks 128..383 -> c2p1[j] = 1 + sum_d clusters[j][d]^2
// Fragment f = s*8 + t (s = kstep 0..15, t = col-tile 0..7); lane l holds
// B'[col = t*32 + (l&31)][k = s*16 + (l>>5)*8 + v], v = 0..7.
// A uses the same (group,v)->k map, so any HW k-permutation cancels.
// (Mapping verified end-to-end by R1's passing kernel.)
// ---------------------------------------------------------------------------
__global__ __launch_bounds__(64) void pre_kernel(const float* __restrict__ clusters,
                                                 _Float16* __restrict__ bfrag,
                                                 float* __restrict__ c2p1) {
    int b = blockIdx.x;
    int l = threadIdx.x;
    if (b < 128) {
        int s   = b >> 3;             // 0..15 (K step)
        int t   = b & 7;              // 0..7  (col tile)
        int col = t * 32 + (l & 31);
        int k0  = s * 16 + (l >> 5) * 8;
        const f32x4* p = reinterpret_cast<const f32x4*>(clusters + col * DIM + k0);
        f32x4 a = p[0];
        f32x4 c = p[1];
        f16x8 h;
        h[0] = (_Float16)(-2.0f * a[0]); h[1] = (_Float16)(-2.0f * a[1]);
        h[2] = (_Float16)(-2.0f * a[2]); h[3] = (_Float16)(-2.0f * a[3]);
        h[4] = (_Float16)(-2.0f * c[0]); h[5] = (_Float16)(-2.0f * c[1]);
        h[6] = (_Float16)(-2.0f * c[2]); h[7] = (_Float16)(-2.0f * c[3]);
        reinterpret_cast<f16x8*>(bfrag)[b * 64 + l] = h;
    } else {
        int j = b - 128;
        const f32x4* p = reinterpret_cast<const f32x4*>(clusters + j * DIM);
        f32x4 v = p[l];
        float s = v[0] * v[0] + v[1] * v[1] + v[2] * v[2] + v[3] * v[3];
#pragma unroll
        for (int m = 32; m >= 1; m >>= 1) s += __shfl_xor(s, m, 64);
        if (l == 0) c2p1[j] = 1.0f + s;
    }
}

// ---------------------------------------------------------------------------
// Main kernel: 2048 blocks x 64 threads (1 wave). Wave owns 32 rows x 256
// cols as 8 tiles of mfma_f32_32x32x16_f16 over K=256 (16 steps).
// acc = -2*x.c ; d = x2 + (1+c2) + acc ; q = rcp(d); wave-local row-norm.
// ---------------------------------------------------------------------------
__global__ __launch_bounds__(64, 1) void cluster_kernel(const float* __restrict__ x,
                                                        const f16x8* __restrict__ bfrag,
                                                        const float* __restrict__ c2p1,
                                                        float* __restrict__ out) {
    __shared__ __align__(16) _Float16 Xs[32 * DIM];   // 16 KB, wave-private

    const int lane = threadIdx.x;
    const int r32  = lane & 31;
    const int g2   = lane >> 5;
    const size_t row0 = (size_t)blockIdx.x * 32;

    // ---- stage: 32 coalesced row-chunk loads (chunk c = row c, 1 KB/inst) ----
    f32x4 ld[32];
#pragma unroll
    for (int c = 0; c < 32; ++c)
        ld[c] = *reinterpret_cast<const f32x4*>(x + (row0 + c) * DIM + lane * 4);

#pragma unroll
    for (int c = 0; c < 32; ++c) {
        f16x4 h;
        h[0] = (_Float16)ld[c][0]; h[1] = (_Float16)ld[c][1];
        h[2] = (_Float16)ld[c][2]; h[3] = (_Float16)ld[c][3];
        int g16 = lane >> 1, sub = lane & 1;
        int byte = c * 512 + ((g16 ^ (c & 15)) << 4) + sub * 8;
        *reinterpret_cast<f16x4*>(reinterpret_cast<char*>(Xs) + byte) = h;
    }
    // no __syncthreads: LDS is wave-private; lgkmcnt ordering suffices.

    // ---- MFMA: 8 col-tiles x 16 K-steps; x2 accumulated from A frags ----
    f32x16 acc[8] = {};
    const f16x8* bp = bfrag + lane;
    float x2p = 0.0f;
#pragma unroll
    for (int s = 0; s < 16; ++s) {
        f16x8 a8 = *reinterpret_cast<const f16x8*>(
            reinterpret_cast<const char*>(Xs)
            + r32 * 512 + (((s * 2 + g2) ^ (r32 & 15)) << 4));
#pragma unroll
        for (int v = 0; v < 8; ++v) {
            float xv = (float)a8[v];
            x2p += xv * xv;
        }
#pragma unroll
        for (int t = 0; t < 8; ++t) {
            f16x8 bf = bp[(s * 8 + t) * 64];
            acc[t] = __builtin_amdgcn_mfma_f32_32x32x16_f16(a8, bf, acc[t], 0, 0, 0);
        }
    }
    float x2full = x2p + __shfl_xor(x2p, 32, 64);   // x2[row r32], all lanes

    // ---- c2p1 for this lane's columns (L2-hot) ----
    float c2v[8];
#pragma unroll
    for (int t = 0; t < 8; ++t) c2v[t] = c2p1[t * 32 + r32];

    // ---- epilogue: d = x2 + (1+c2) + acc ; q = rcp(d); row-normalize ----
    // C/D layout (R1-verified): col = lane&31, row = (j&3) + 8*(j>>2) + 4*g2.
#pragma unroll
    for (int j = 0; j < 16; ++j) {
        const int rowloc = (j & 3) + 8 * (j >> 2) + 4 * g2;
        float x2j = __shfl(x2full, rowloc, 64);
        float rs = 0.0f;
#pragma unroll
        for (int t = 0; t < 8; ++t) {
            float d = x2j + c2v[t] + acc[t][j];
            float q = __builtin_amdgcn_rcpf(d);
            acc[t][j] = q;
            rs += q;
        }
        // row lives in one 32-lane half: reduce masks 1..16
        rs += __shfl_xor(rs, 1, 64);
        rs += __shfl_xor(rs, 2, 64);
        rs += __shfl_xor(rs, 4, 64);
        rs += __shfl_xor(rs, 8, 64);
        rs += __shfl_xor(rs, 16, 64);
        float rn = __builtin_amdgcn_rcpf(rs);
        float* op = out + (row0 + rowloc) * NCLUST + r32;
#pragma unroll
        for (int t = 0; t < 8; ++t) op[t * 32] = acc[t][j] * rn;
    }
}

extern "C" void kernel_launch(void* const* d_in, const int* in_sizes, int n_in,
                              void* d_out, int out_size, void* d_ws, size_t ws_size,
                              hipStream_t stream) {
    const float* x        = (const float*)d_in[0];
    const float* clusters = (const float*)d_in[1];
    float* out = (float*)d_out;

    _Float16* bfrag = (_Float16*)d_ws;                       // 128*64*16B = 128 KB
    float*    c2p1  = (float*)((char*)d_ws + 128 * 64 * 16); // 1 KB

    pre_kernel<<<384, 64, 0, stream>>>(clusters, bfrag, c2p1);

    int nrows = in_sizes[0] / DIM;          // 65536
    int grid  = nrows / 32;                 // 2048
    cluster_kernel<<<grid, 64, 0, stream>>>(x, (const f16x8*)bfrag, c2p1, out);
}

// Round 15
// 31.505 us; speedup vs baseline: 1.3627x; 1.3627x over previous
//
#include <hip/hip_runtime.h>

// ClusteringLayer: q[n,k] = normalize_k( 1 / (1 + ||x_n - c_k||^2) )
// x: [65536,256] fp32, clusters: [256,256] fp32, out: [65536,256] fp32.
// R14: fp8 (OCP e4m3) both operands via mfma_f32_16x16x32_fp8_fp8.
// B' = -2*clusters as fp8 fragments = 64 KB LDS -> 2 blocks/CU co-resident
// (whole 512-block grid resident); LDS B-reads 1 MB/CU; af 16 VGPRs.
// Structure = R8 (1 barrier, wave-local row-norm, direct stores), but with
// 8-wave blocks x 2 per CU so barriers couple only half the CU's waves.
// x2/c2 in fp32 -> dist2 err ~ +-9 tail -> |dq| ~ 3e-5 < 1.26e-4 threshold.

typedef float f32x4 __attribute__((ext_vector_type(4)));

#define DIM    256
#define NCLUST 256

__device__ inline int pk4_fp8(float a, float b, float c, float d) {
    int w = __builtin_amdgcn_cvt_pk_fp8_f32(a, b, 0, false);   // bytes 0,1
    w = __builtin_amdgcn_cvt_pk_fp8_f32(c, d, w, true);        // bytes 2,3
    return w;
}

// ---------------------------------------------------------------------------
// Pre-kernel: blocks 0..127 -> B' = (-2*clusters) as fp8 fragments (64 KB)
//             blocks 128..383 -> c2p1[j] = 1 + sum_d clusters[j][d]^2
// Fragment f = s*16 + t; lane l holds 8 bytes:
// B'[col = t*16 + (l&15)][k = s*32 + (l>>4)*8 + v], v = 0..7 (byte v).
// A uses the same (group,v)->k map, so any HW k-permutation cancels.
// ---------------------------------------------------------------------------
__global__ __launch_bounds__(64) void pre_kernel(const float* __restrict__ clusters,
                                                 int* __restrict__ bfrag,   // as int2 pairs
                                                 float* __restrict__ c2p1) {
    int b = blockIdx.x;
    int l = threadIdx.x;
    if (b < 128) {
        int s   = b >> 4;
        int t   = b & 15;
        int col = t * 16 + (l & 15);
        int k0  = s * 32 + (l >> 4) * 8;
        const f32x4* p = reinterpret_cast<const f32x4*>(clusters + col * DIM + k0);
        f32x4 a = p[0];
        f32x4 c = p[1];
        int lo = pk4_fp8(-2.0f * a[0], -2.0f * a[1], -2.0f * a[2], -2.0f * a[3]);
        int hi = pk4_fp8(-2.0f * c[0], -2.0f * c[1], -2.0f * c[2], -2.0f * c[3]);
        bfrag[(b * 64 + l) * 2]     = lo;
        bfrag[(b * 64 + l) * 2 + 1] = hi;
    } else {
        int j = b - 128;
        const f32x4* p = reinterpret_cast<const f32x4*>(clusters + j * DIM);
        f32x4 v = p[l];
        float s = v[0] * v[0] + v[1] * v[1] + v[2] * v[2] + v[3] * v[3];
#pragma unroll
        for (int m = 32; m >= 1; m >>= 1) s += __shfl_xor(s, m, 64);
        if (l == 0) c2p1[j] = 1.0f + s;
    }
}

// ---------------------------------------------------------------------------
// Main kernel: 512 blocks x 512 threads (8 waves); 2 blocks/CU resident
// (64 KB LDS each) -> entire grid on-chip. Wave owns tile (blockIdx*8+wave):
// 16 rows x all 256 cols. acc = -2*x.c ; d = x2 + (1+c2) + acc ;
// q = rcp(d); wave-local row-norm; direct sector-efficient stores.
// ---------------------------------------------------------------------------
__global__ __launch_bounds__(512, 2) void cluster_kernel(const float* __restrict__ x,
                                                         const f32x4* __restrict__ bfrag,
                                                         const float* __restrict__ c2p1,
                                                         float* __restrict__ out) {
    __shared__ __align__(16) char Bs[65536];   // 64 KB fp8 fragments

    const int tid  = threadIdx.x;
    const int lane = tid & 63;
    const int wave = tid >> 6;
    const int cl   = lane & 15;
    const int g    = lane >> 4;
    const int tile = blockIdx.x * 8 + wave;

    // ---- issue this wave's X loads first (HBM; 16 x 16B per lane) ----
    f32x4 ld[16];
    {
        const float* xr = x + (size_t)(tile * 16 + cl) * DIM + g * 8;
#pragma unroll
        for (int s = 0; s < 8; ++s) {
            ld[2 * s]     = *reinterpret_cast<const f32x4*>(xr + s * 32);
            ld[2 * s + 1] = *reinterpret_cast<const f32x4*>(xr + s * 32 + 4);
        }
    }

    // ---- stage fp8 B' fragments into LDS (64 KB, L2-hot, coalesced) ----
    {
        f32x4* dst = reinterpret_cast<f32x4*>(Bs);
#pragma unroll
        for (int i = 0; i < 8; ++i) {
            int idx = i * 512 + tid;
            dst[idx] = bfrag[idx];
        }
    }
    __syncthreads();   // the only barrier (couples 8 waves, not 16)

    // ---- build fp8 A fragments + fp32 x2 (ld dies here) ----
    long af[8];
    float x2p = 0.0f;
#pragma unroll
    for (int s = 0; s < 8; ++s) {
        f32x4 a = ld[2 * s], b = ld[2 * s + 1];
        x2p += a[0]*a[0] + a[1]*a[1] + a[2]*a[2] + a[3]*a[3]
             + b[0]*b[0] + b[1]*b[1] + b[2]*b[2] + b[3]*b[3];
        unsigned lo = (unsigned)pk4_fp8(a[0], a[1], a[2], a[3]);
        unsigned hi = (unsigned)pk4_fp8(b[0], b[1], b[2], b[3]);
        af[s] = (long)(((unsigned long)hi << 32) | lo);
    }
    float x2full = x2p + __shfl_xor(x2p, 16, 64);
    x2full += __shfl_xor(x2full, 32, 64);      // x2 of row (tile*16 + cl)

    // ---- MFMA: 16 rows x 256 cols, fp8 B from LDS (ds_read_b64, 2-way=free) ----
    f32x4 acc[16];
#pragma unroll
    for (int t = 0; t < 16; ++t) {
        acc[t][0] = 0.f; acc[t][1] = 0.f; acc[t][2] = 0.f; acc[t][3] = 0.f;
    }
    const char* bsb = Bs + lane * 8;
    __builtin_amdgcn_s_setprio(1);
#pragma unroll
    for (int s = 0; s < 8; ++s) {
#pragma unroll
        for (int t = 0; t < 16; ++t) {
            long bf = *reinterpret_cast<const long*>(bsb + (s * 16 + t) * 512);
            acc[t] = __builtin_amdgcn_mfma_f32_16x16x32_fp8_fp8(
                af[s], bf, acc[t], 0, 0, 0);
        }
    }
    __builtin_amdgcn_s_setprio(0);

    // ---- c2p1 for this lane's columns (L2-hot; loaded late on purpose) ----
    float c2v[16];
#pragma unroll
    for (int t = 0; t < 16; ++t) c2v[t] = c2p1[t * 16 + cl];

    // ---- epilogue: d = x2 + (1+c2) + acc ; q = rcp(d); row-normalize ----
    // C/D layout: col = lane&15, row = (lane>>4)*4 + reg.
    float x2j[4];
#pragma unroll
    for (int j = 0; j < 4; ++j) x2j[j] = __shfl(x2full, g * 4 + j, 64);

    float rsum[4] = {0.f, 0.f, 0.f, 0.f};
#pragma unroll
    for (int t = 0; t < 16; ++t) {
#pragma unroll
        for (int j = 0; j < 4; ++j) {
            float d = x2j[j] + c2v[t] + acc[t][j];
            float q = __builtin_amdgcn_rcpf(d);
            acc[t][j] = q;
            rsum[j] += q;
        }
    }
#pragma unroll
    for (int j = 0; j < 4; ++j) {
        float v = rsum[j];
        v += __shfl_xor(v, 1, 64); v += __shfl_xor(v, 2, 64);
        v += __shfl_xor(v, 4, 64); v += __shfl_xor(v, 8, 64);
        rsum[j] = __builtin_amdgcn_rcpf(v);
    }
    float* ob = out + (size_t)(tile * 16) * NCLUST;
#pragma unroll
    for (int t = 0; t < 16; ++t)
#pragma unroll
        for (int j = 0; j < 4; ++j)
            ob[(g * 4 + j) * NCLUST + t * 16 + cl] = acc[t][j] * rsum[j];
}

extern "C" void kernel_launch(void* const* d_in, const int* in_sizes, int n_in,
                              void* d_out, int out_size, void* d_ws, size_t ws_size,
                              hipStream_t stream) {
    const float* x        = (const float*)d_in[0];
    const float* clusters = (const float*)d_in[1];
    float* out = (float*)d_out;

    int*   bfrag = (int*)d_ws;                        // 128*64*8B = 64 KB
    float* c2p1  = (float*)((char*)d_ws + 65536);     // 1 KB

    pre_kernel<<<384, 64, 0, stream>>>(clusters, bfrag, c2p1);

    int nrows = in_sizes[0] / DIM;              // 65536
    int grid  = nrows / (8 * 16);               // 512
    cluster_kernel<<<grid, 512, 0, stream>>>(x, (const f32x4*)bfrag, c2p1, out);
}